// Round 18
// baseline (349.767 us; speedup 1.0000x reference)
//
#include <hip/hip_runtime.h>

#define NN 50000      // nodes
#define NE 600000     // edges
#define HC 128        // hidden channels
#define CHN 32        // chunk size
#define NG 64         // graphs
#define LN_EPS 1e-5f

typedef unsigned short ushort_t;
typedef unsigned int uint_t;
typedef _Float16 half2_t __attribute__((ext_vector_type(2)));

__device__ __forceinline__ ushort_t f2h(float f) {    // f32 -> f16 (RNE)
    _Float16 h = (_Float16)f;
    return __builtin_bit_cast(ushort_t, h);
}
__device__ __forceinline__ float h2f(ushort_t s) {
    _Float16 h = __builtin_bit_cast(_Float16, s);
    return (float)h;
}
__device__ __forceinline__ uint_t pkh(float e, float o) {   // pack 2 f16
    return (uint_t)f2h(e) | ((uint_t)f2h(o) << 16);
}
__device__ __forceinline__ half2_t bch(uint_t u) {
    return __builtin_bit_cast(half2_t, u);
}
// z += a . b for packed f16 pairs, f32 accumulate (v_dot2_f32_f16)
__device__ __forceinline__ float dot2h(uint_t a, uint_t b, float c) {
#if __has_builtin(__builtin_amdgcn_fdot2)
    return __builtin_amdgcn_fdot2(__builtin_bit_cast(half2_t, a),
                                  __builtin_bit_cast(half2_t, b), c, false);
#else
    half2_t ha = __builtin_bit_cast(half2_t, a);
    half2_t hb = __builtin_bit_cast(half2_t, b);
    c = fmaf((float)ha.x, (float)hb.x, c);
    c = fmaf((float)ha.y, (float)hb.y, c);
    return c;
#endif
}

// ---------------- CSR build ----------------

__global__ void __launch_bounds__(256) k_hist(const int* __restrict__ ei, int* __restrict__ cnt) {
    int e = blockIdx.x * 256 + threadIdx.x;
    if (e >= NE) return;
    int s = ei[e], d = ei[NE + e];
    if (s != d) atomicAdd(&cnt[d], 1);
}

#define SC_BLOCKS 49   // ceil(50000/1024)

__global__ void __launch_bounds__(256) k_scanA(const int* __restrict__ cnt, int* __restrict__ blocksum) {
    int b = blockIdx.x, t = threadIdx.x;
    int idx = b * 1024 + t * 4;
    int4 v = make_int4(0, 0, 0, 0);
    if (idx + 3 < NN) v = *(const int4*)&cnt[idx];
    else {
        if (idx + 0 < NN) v.x = cnt[idx + 0];
        if (idx + 1 < NN) v.y = cnt[idx + 1];
        if (idx + 2 < NN) v.z = cnt[idx + 2];
        if (idx + 3 < NN) v.w = cnt[idx + 3];
    }
    int s = v.x + v.y + v.z + v.w;
    for (int m = 1; m < 64; m <<= 1) s += __shfl_xor(s, m, 64);
    __shared__ int ws[4];
    if ((t & 63) == 0) ws[t >> 6] = s;
    __syncthreads();
    if (t == 0) blocksum[b] = ws[0] + ws[1] + ws[2] + ws[3];
}

__global__ void __launch_bounds__(64) k_scanB(const int* __restrict__ blocksum, int* __restrict__ blockoff) {
    int t = threadIdx.x;
    int v = (t < SC_BLOCKS) ? blocksum[t] : 0;
    int inc = v;
    for (int d = 1; d < 64; d <<= 1) { int u = __shfl_up(inc, d, 64); if (t >= d) inc += u; }
    if (t < SC_BLOCKS) blockoff[t + 1] = inc;
    if (t == 0) blockoff[0] = 0;
}

__global__ void __launch_bounds__(256) k_scanC(const int* __restrict__ cnt, const int* __restrict__ blockoff,
                                               int* __restrict__ row_ptr) {
    int b = blockIdx.x, t = threadIdx.x;
    int idx = b * 1024 + t * 4;
    int4 v = make_int4(0, 0, 0, 0);
    if (idx + 3 < NN) v = *(const int4*)&cnt[idx];
    else {
        if (idx + 0 < NN) v.x = cnt[idx + 0];
        if (idx + 1 < NN) v.y = cnt[idx + 1];
        if (idx + 2 < NN) v.z = cnt[idx + 2];
        if (idx + 3 < NN) v.w = cnt[idx + 3];
    }
    int s = v.x + v.y + v.z + v.w;
    int lane = t & 63, w = t >> 6;
    int inc = s;
    for (int d = 1; d < 64; d <<= 1) { int u = __shfl_up(inc, d, 64); if (lane >= d) inc += u; }
    __shared__ int wsum[4];
    if (lane == 63) wsum[w] = inc;
    __syncthreads();
    int off = blockoff[b];
    for (int i = 0; i < w; ++i) off += wsum[i];
    int excl = off + inc - s;
    if (idx + 0 < NN) row_ptr[idx + 0] = excl;
    if (idx + 1 < NN) row_ptr[idx + 1] = excl + v.x;
    if (idx + 2 < NN) row_ptr[idx + 2] = excl + v.x + v.y;
    if (idx + 3 < NN) row_ptr[idx + 3] = excl + v.x + v.y + v.z;
    if (b == 0 && t == 0) row_ptr[NN] = blockoff[SC_BLOCKS];
}

__global__ void __launch_bounds__(256) k_fill(const int* __restrict__ ei, const int* __restrict__ row_ptr,
                                              int* __restrict__ fill, int* __restrict__ col) {
    int e = blockIdx.x * 256 + threadIdx.x;
    if (e >= NE) return;
    int s = ei[e], d = ei[NE + e];
    if (s != d) {
        int pos = atomicAdd(&fill[d], 1);
        col[row_ptr[d] + pos] = s;
    }
}

// ---------------- prep: pack W_tm to f16 pairs ([cp][k], coalesced) + zero cnt/fil ----------------

__global__ void __launch_bounds__(256) k_prep(const float* __restrict__ Wtm, uint_t* __restrict__ Wg,
                                              int* __restrict__ cnt) {
    int i = blockIdx.x * 256 + threadIdx.x;
    if (i < 32 * 128) {                           // 4096 entries
        int cp = i >> 5, kk = i & 31;
        Wg[i] = pkh(Wtm[(2 * cp) * CHN + kk], Wtm[(2 * cp + 1) * CHN + kk]);
    }
    for (int z = i; z < 2 * NN; z += gridDim.x * 256) cnt[z] = 0;   // cnt + fil
}

// ---------------- input MLP: h2 = f16(LN(relu(x @ W_in + b_in))); also zeros tm ----------------

#define MLP_NB 8
#define MLP_GROUPS (NN / MLP_NB)   // 6250, exact

__global__ void __launch_bounds__(256) k_mlp(const float* __restrict__ x, const float* __restrict__ W,
                                             const float* __restrict__ b, const float* __restrict__ g,
                                             const float* __restrict__ be, ushort_t* __restrict__ h2,
                                             ushort_t* __restrict__ tm) {
    // zero last_tm_signal (f16, u32-zero covers 2 entries; runs long before flayer)
    uint_t* tz = (uint_t*)tm;
    for (int z = blockIdx.x * 256 + threadIdx.x; z < NN * CHN / 2; z += gridDim.x * 256) tz[z] = 0u;
    __shared__ float xs[4][MLP_NB][HC];     // 16 KB
    int tid = threadIdx.x;
    int wave = tid >> 6, lane = tid & 63;
    float bx = b[2 * lane],  by = b[2 * lane + 1];
    float gx = g[2 * lane],  gy = g[2 * lane + 1];
    float bex = be[2 * lane], bey = be[2 * lane + 1];
    for (int grp = blockIdx.x * 4 + wave; grp < MLP_GROUPS; grp += gridDim.x * 4) {
        int base = grp * MLP_NB;
        #pragma unroll
        for (int nb = 0; nb < MLP_NB; ++nb) {
            float2 xv = *(const float2*)&x[(size_t)(base + nb) * HC + 2 * lane];
            *(float2*)&xs[wave][nb][2 * lane] = xv;
        }
        float ax[MLP_NB], ay[MLP_NB];
        #pragma unroll
        for (int nb = 0; nb < MLP_NB; ++nb) { ax[nb] = bx; ay[nb] = by; }
        // wave-local LDS: compiler inserts lgkmcnt waits; no block barrier needed
        for (int c = 0; c < HC; c += 4) {
            float2 wv0 = *(const float2*)&W[(c + 0) * HC + 2 * lane];
            float2 wv1 = *(const float2*)&W[(c + 1) * HC + 2 * lane];
            float2 wv2 = *(const float2*)&W[(c + 2) * HC + 2 * lane];
            float2 wv3 = *(const float2*)&W[(c + 3) * HC + 2 * lane];
            #pragma unroll
            for (int nb = 0; nb < MLP_NB; ++nb) {
                float4 xv = *(const float4*)&xs[wave][nb][c];
                ax[nb] = fmaf(xv.x, wv0.x, ax[nb]); ay[nb] = fmaf(xv.x, wv0.y, ay[nb]);
                ax[nb] = fmaf(xv.y, wv1.x, ax[nb]); ay[nb] = fmaf(xv.y, wv1.y, ay[nb]);
                ax[nb] = fmaf(xv.z, wv2.x, ax[nb]); ay[nb] = fmaf(xv.z, wv2.y, ay[nb]);
                ax[nb] = fmaf(xv.w, wv3.x, ax[nb]); ay[nb] = fmaf(xv.w, wv3.y, ay[nb]);
            }
        }
        #pragma unroll
        for (int nb = 0; nb < MLP_NB; ++nb) {
            float a0 = fmaxf(ax[nb], 0.f), a1 = fmaxf(ay[nb], 0.f);
            float sm = a0 + a1;
            for (int m = 1; m < 64; m <<= 1) sm += __shfl_xor(sm, m, 64);
            float mu = sm * (1.f / 128.f);
            float d0 = a0 - mu, d1 = a1 - mu;
            float vv = d0 * d0 + d1 * d1;
            for (int m = 1; m < 64; m <<= 1) vv += __shfl_xor(vv, m, 64);
            float inv = rsqrtf(vv * (1.f / 128.f) + LN_EPS);
            float ox = d0 * inv * gx + bex;
            float oy = d1 * inv * gy + bey;
            *(uint_t*)&h2[(size_t)(base + nb) * HC + 2 * lane] = pkh(ox, oy);
        }
    }
}

// ---------------- fused layer: gather + mean + gating + mix + LN (f16 state) ----------------
// R15 occupancy-first shape, gather restructured to 4 ch/lane + edge-parity
// halves: lane l32 owns channels 4*l32..+3; lanes<32 take even edges, >=32 odd,
// each loading 8 B (uint2) -> one load instruction fetches TWO rows (still
// 256 B/row cross-lane coalesced). Per edge: ~0.5 load + 0.5 shfl + 1 masked
// pk_add (was 1+1+1). Parity sums combine with 2 shfl_xor(32). Downstream uses
// the R10-verified 4ch/lane math: sig = gate l32, width-32 LN reduce.

__global__ void __launch_bounds__(256) k_flayer(
        const ushort_t* __restrict__ h2in, ushort_t* __restrict__ h2out,
        const int* __restrict__ row_ptr, const int* __restrict__ col,
        const uint_t* __restrict__ Wg, const float* __restrict__ btm,
        const float* __restrict__ gall, const float* __restrict__ ball,
        ushort_t* __restrict__ tm, int layer) {
    __shared__ uint_t hm_pk[4][2][64];   // 2 KB: [wave][h|m][pair]
    int tid = threadIdx.x;
    int wave = tid >> 6, lane = tid & 63;
    int l32 = lane & 31, half = lane >> 5;
    int node = blockIdx.x * 4 + wave;
    int r0 = row_ptr[node], r1 = row_ptr[node + 1];
    int deg = r1 - r0;
    float tmo = h2f(tm[(size_t)node * CHN + l32]);   // prefetch, hides under gather
    float bk  = btm[l32];
    float4 gv = *(const float4*)&gall[layer * HC + 4 * l32];
    float4 bv = *(const float4*)&ball[layer * HC + 4 * l32];
    // ---- gather: this half sums edges of its parity, 4 ch/lane via uint2 ----
    half2_t acc0 = (half2_t)(_Float16)0, acc1 = (half2_t)(_Float16)0;
    for (int base = 0; base < deg; base += 64) {
        int nIdx = min(64, deg - base);
        int myc = (base + lane < deg) ? col[r0 + base + lane] : 0;
        int tmax = (nIdx + 1) >> 1;              // row-pair slots
        int t = 0;
        for (; t + 4 <= tmax; t += 4) {          // 8 rows in flight (4 uint2/half)
            int j0 = 2 * t + half, j1 = j0 + 2, j2 = j0 + 4, j3 = j0 + 6;
            int s0 = __shfl(myc, j0 & 63, 64);
            int s1 = __shfl(myc, j1 & 63, 64);
            int s2 = __shfl(myc, j2 & 63, 64);
            int s3 = __shfl(myc, j3 & 63, 64);
            uint2 v0 = *(const uint2*)&h2in[(size_t)s0 * HC + 4 * l32];
            uint2 v1 = *(const uint2*)&h2in[(size_t)s1 * HC + 4 * l32];
            uint2 v2 = *(const uint2*)&h2in[(size_t)s2 * HC + 4 * l32];
            uint2 v3 = *(const uint2*)&h2in[(size_t)s3 * HC + 4 * l32];
            if (j0 < nIdx) { acc0 += bch(v0.x); acc1 += bch(v0.y); }
            if (j1 < nIdx) { acc0 += bch(v1.x); acc1 += bch(v1.y); }
            if (j2 < nIdx) { acc0 += bch(v2.x); acc1 += bch(v2.y); }
            if (j3 < nIdx) { acc0 += bch(v3.x); acc1 += bch(v3.y); }
        }
        for (; t < tmax; ++t) {
            int j = 2 * t + half;
            int s = __shfl(myc, j & 63, 64);
            uint2 v = *(const uint2*)&h2in[(size_t)s * HC + 4 * l32];
            if (j < nIdx) { acc0 += bch(v.x); acc1 += bch(v.y); }
        }
    }
    // combine parities: both halves end with full sums
    {
        uint_t u0 = __builtin_bit_cast(uint_t, acc0);
        uint_t u1 = __builtin_bit_cast(uint_t, acc1);
        acc0 += bch((uint_t)__shfl_xor((int)u0, 32, 64));
        acc1 += bch((uint_t)__shfl_xor((int)u1, 32, 64));
    }
    float a0 = (float)acc0.x, a1 = (float)acc0.y;
    float a2 = (float)acc1.x, a3 = (float)acc1.y;
    // ---- self row, mean ----
    uint2 hv = *(const uint2*)&h2in[(size_t)node * HC + 4 * l32];
    float h0 = h2f((ushort_t)(hv.x & 0xFFFFu)), h1 = h2f((ushort_t)(hv.x >> 16));
    float h2v = h2f((ushort_t)(hv.y & 0xFFFFu)), h3 = h2f((ushort_t)(hv.y >> 16));
    float invdeg = 1.f / (float)(deg + 1);
    float m0 = (a0 + h0) * invdeg, m1 = (a1 + h1) * invdeg;
    float m2 = (a2 + h2v) * invdeg, m3 = (a3 + h3) * invdeg;
    if (half == 0) {
        *(uint2*)&hm_pk[wave][0][2 * l32] = hv;                      // raw self row
        uint2 mp; mp.x = pkh(m0, m1); mp.y = pkh(m2, m3);
        *(uint2*)&hm_pk[wave][1][2 * l32] = mp;
    }
    // wave-local LDS: compiler inserts the lgkmcnt wait; no block barrier needed
    // ---- z_k: half 0 = h . W[0:128,k], half 1 = m . W[128:256,k] (v_dot2) ----
    const uint_t* sp = &hm_pk[wave][half][0];
    const uint_t* wp = Wg + (size_t)(half * 64) * CHN + l32;
    float z = 0.f;
    #pragma unroll
    for (int i = 0; i < 16; ++i) {
        uint4 s4 = *(const uint4*)&sp[4 * i];       // LDS broadcast
        uint_t w0 = wp[(4 * i + 0) * CHN];          // cross-lane coalesced, L1-hot
        uint_t w1 = wp[(4 * i + 1) * CHN];
        uint_t w2 = wp[(4 * i + 2) * CHN];
        uint_t w3 = wp[(4 * i + 3) * CHN];
        z = dot2h(s4.x, w0, z);
        z = dot2h(s4.y, w1, z);
        z = dot2h(s4.z, w2, z);
        z = dot2h(s4.w, w3, z);
    }
    z += __shfl_xor(z, 32, 64);      // combine halves -> full z_k on all lanes
    z += bk;
    // ---- softmax over 32 gates (width-32: halves identical) ----
    float mx = z;
    for (int m = 1; m < 32; m <<= 1) mx = fmaxf(mx, __shfl_xor(mx, m, 32));
    float e = __expf(z - mx);
    float se = e;
    for (int m = 1; m < 32; m <<= 1) se += __shfl_xor(se, m, 32);
    float p = e / se;
    // inclusive cumsum over gate index
    float cum = p;
    for (int d = 1; d < 32; d <<= 1) {
        float t2 = __shfl_up(cum, d, 32);
        if (l32 >= d) cum += t2;
    }
    float raw = tmo + (1.f - tmo) * cum;
    if (half == 0) tm[(size_t)node * CHN + l32] = f2h(raw);
    // sig for this lane's 4 channels: gate = (4*l32)/4 = l32
    float sig = __shfl(raw, l32, 64);
    float om = 1.f - sig;
    float v0 = h0 * sig + m0 * om;
    float v1 = h1 * sig + m1 * om;
    float v2 = h2v * sig + m2 * om;
    float v3 = h3 * sig + m3 * om;
    // ---- LN over 128 ch: width-32 reduce (each half holds a full copy) ----
    float sm = v0 + v1 + v2 + v3;
    for (int m = 1; m < 32; m <<= 1) sm += __shfl_xor(sm, m, 32);
    float mu = sm * (1.f / 128.f);
    float d0 = v0 - mu, d1 = v1 - mu, d2 = v2 - mu, d3 = v3 - mu;
    float vv = d0 * d0 + d1 * d1 + d2 * d2 + d3 * d3;
    for (int m = 1; m < 32; m <<= 1) vv += __shfl_xor(vv, m, 32);
    float inv = rsqrtf(vv * (1.f / 128.f) + LN_EPS);
    if (half == 0) {
        uint2 o;
        o.x = pkh(d0 * inv * gv.x + bv.x, d1 * inv * gv.y + bv.y);
        o.y = pkh(d2 * inv * gv.z + bv.z, d3 * inv * gv.w + bv.w);
        *(uint2*)&h2out[(size_t)node * HC + 4 * l32] = o;
    }
}

// ---------------- global mean pool (batch is sorted), f16 input ----------------

__global__ void __launch_bounds__(1024) k_pool(const ushort_t* __restrict__ h2, const int* __restrict__ batch,
                                               float* __restrict__ out) {
    __shared__ float red[8][HC];
    int g = blockIdx.x;
    int tid = threadIdx.x;
    int c = tid & (HC - 1);
    int w = tid >> 7;          // 0..7 node-slice
    int a = 0, bnd = NN;
    while (a < bnd) { int mid = (a + bnd) >> 1; if (batch[mid] < g) a = mid + 1; else bnd = mid; }
    int start = a;
    bnd = NN;
    while (a < bnd) { int mid = (a + bnd) >> 1; if (batch[mid] <= g) a = mid + 1; else bnd = mid; }
    int end = a;
    float acc = 0.f;
    for (int n = start + w; n < end; n += 8) acc += h2f(h2[(size_t)n * HC + c]);
    red[w][c] = acc;
    __syncthreads();
    if (w == 0) {
        float s = red[0][c] + red[1][c] + red[2][c] + red[3][c]
                + red[4][c] + red[5][c] + red[6][c] + red[7][c];
        int count = end - start;
        out[g * HC + c] = s / (float)max(count, 1);
    }
}

// ---------------- launch ----------------

extern "C" void kernel_launch(void* const* d_in, const int* in_sizes, int n_in,
                              void* d_out, int out_size, void* d_ws, size_t ws_size,
                              hipStream_t stream) {
    const float* x     = (const float*)d_in[0];
    const int*   ei    = (const int*)d_in[1];
    const int*   batch = (const int*)d_in[2];
    const float* W_in  = (const float*)d_in[3];
    const float* b_in  = (const float*)d_in[4];
    const float* g_in  = (const float*)d_in[5];
    const float* be_in = (const float*)d_in[6];
    const float* W_tm  = (const float*)d_in[7];
    const float* b_tm  = (const float*)d_in[8];
    const float* tm_g  = (const float*)d_in[9];
    const float* tm_b  = (const float*)d_in[10];
    float* out = (float*)d_out;

    char* ws = (char*)d_ws;
    int*      cnt = (int*)(ws + 0);              // NN ints
    int*      fil = (int*)(ws + 200000);         // NN ints (contiguous after cnt)
    int*      rp  = (int*)(ws + 400000);         // NN+1 ints
    int*      col = (int*)(ws + 600004);         // NE ints   (ends at 3,000,004)
    ushort_t* h2A = (ushort_t*)(ws + 3000064);   // NN*HC f16 (12.8 MB)
    ushort_t* h2B = (ushort_t*)(ws + 15800064);  // NN*HC f16 (12.8 MB)
    ushort_t* tm  = (ushort_t*)(ws + 28600064);  // NN*CHN f16 (3.2 MB)
    int*      bsum = (int*)(ws + 35000064);      // SC_BLOCKS ints
    int*      boff = (int*)(ws + 35000320);      // SC_BLOCKS+1 ints
    uint_t*   Wg   = (uint_t*)(ws + 35000576);   // 4096 u32 packed f16 W (16 KB, [cp][k])

    k_prep<<<64, 256, 0, stream>>>(W_tm, Wg, cnt);      // pack W + zero cnt/fil
    k_hist<<<(NE + 255) / 256, 256, 0, stream>>>(ei, cnt);
    k_scanA<<<SC_BLOCKS, 256, 0, stream>>>(cnt, bsum);
    k_scanB<<<1, 64, 0, stream>>>(bsum, boff);
    k_scanC<<<SC_BLOCKS, 256, 0, stream>>>(cnt, boff, rp);
    k_fill<<<(NE + 255) / 256, 256, 0, stream>>>(ei, rp, fil, col);

    k_mlp<<<1563, 256, 0, stream>>>(x, W_in, b_in, g_in, be_in, h2A, tm);  // also zeros tm

    k_flayer<<<NN / 4, 256, 0, stream>>>(h2A, h2B, rp, col, Wg, b_tm, tm_g, tm_b, tm, 0);
    k_flayer<<<NN / 4, 256, 0, stream>>>(h2B, h2A, rp, col, Wg, b_tm, tm_g, tm_b, tm, 1);
    k_flayer<<<NN / 4, 256, 0, stream>>>(h2A, h2B, rp, col, Wg, b_tm, tm_g, tm_b, tm, 2);

    k_pool<<<NG, 1024, 0, stream>>>(h2B, batch, out);
}

// Round 19
// 290.790 us; speedup vs baseline: 1.2028x; 1.2028x over previous
//
#include <hip/hip_runtime.h>

#define NN 50000      // nodes
#define NE 600000     // edges
#define HC 128        // hidden channels
#define CHN 32        // chunk size
#define NG 64         // graphs
#define LN_EPS 1e-5f

typedef unsigned short ushort_t;
typedef unsigned int uint_t;
typedef _Float16 half2_t __attribute__((ext_vector_type(2)));

__device__ __forceinline__ ushort_t f2h(float f) {    // f32 -> f16 (RNE)
    _Float16 h = (_Float16)f;
    return __builtin_bit_cast(ushort_t, h);
}
__device__ __forceinline__ float h2f(ushort_t s) {
    _Float16 h = __builtin_bit_cast(_Float16, s);
    return (float)h;
}
__device__ __forceinline__ uint_t pkh(float e, float o) {   // pack 2 f16
    return (uint_t)f2h(e) | ((uint_t)f2h(o) << 16);
}
// z += a . b for packed f16 pairs, f32 accumulate (v_dot2_f32_f16)
__device__ __forceinline__ float dot2h(uint_t a, uint_t b, float c) {
#if __has_builtin(__builtin_amdgcn_fdot2)
    return __builtin_amdgcn_fdot2(__builtin_bit_cast(half2_t, a),
                                  __builtin_bit_cast(half2_t, b), c, false);
#else
    half2_t ha = __builtin_bit_cast(half2_t, a);
    half2_t hb = __builtin_bit_cast(half2_t, b);
    c = fmaf((float)ha.x, (float)hb.x, c);
    c = fmaf((float)ha.y, (float)hb.y, c);
    return c;
#endif
}

// ---------------- CSR build ----------------

__global__ void __launch_bounds__(256) k_hist(const int* __restrict__ ei, int* __restrict__ cnt) {
    int e = blockIdx.x * 256 + threadIdx.x;
    if (e >= NE) return;
    int s = ei[e], d = ei[NE + e];
    if (s != d) atomicAdd(&cnt[d], 1);
}

#define SC_BLOCKS 49   // ceil(50000/1024)

__global__ void __launch_bounds__(256) k_scanA(const int* __restrict__ cnt, int* __restrict__ blocksum) {
    int b = blockIdx.x, t = threadIdx.x;
    int idx = b * 1024 + t * 4;
    int4 v = make_int4(0, 0, 0, 0);
    if (idx + 3 < NN) v = *(const int4*)&cnt[idx];
    else {
        if (idx + 0 < NN) v.x = cnt[idx + 0];
        if (idx + 1 < NN) v.y = cnt[idx + 1];
        if (idx + 2 < NN) v.z = cnt[idx + 2];
        if (idx + 3 < NN) v.w = cnt[idx + 3];
    }
    int s = v.x + v.y + v.z + v.w;
    for (int m = 1; m < 64; m <<= 1) s += __shfl_xor(s, m, 64);
    __shared__ int ws[4];
    if ((t & 63) == 0) ws[t >> 6] = s;
    __syncthreads();
    if (t == 0) blocksum[b] = ws[0] + ws[1] + ws[2] + ws[3];
}

// scanC now also derives its own block offset from blocksum (scanB folded in):
// wave 0 shuffle-scans the 49 block sums; off(b) = exclusive scan at t=b.

__global__ void __launch_bounds__(256) k_scanC(const int* __restrict__ cnt, const int* __restrict__ blocksum,
                                               int* __restrict__ row_ptr) {
    __shared__ int s_off, s_tot;
    int b = blockIdx.x, t = threadIdx.x;
    if (t < 64) {
        int v = (t < SC_BLOCKS) ? blocksum[t] : 0;
        int inc = v;
        for (int d = 1; d < 64; d <<= 1) { int u = __shfl_up(inc, d, 64); if (t >= d) inc += u; }
        if (t == b) s_off = inc - v;                 // exclusive prefix for this block
        if (t == SC_BLOCKS - 1) s_tot = inc;         // grand total
    }
    int idx = b * 1024 + t * 4;
    int4 v = make_int4(0, 0, 0, 0);
    if (idx + 3 < NN) v = *(const int4*)&cnt[idx];
    else {
        if (idx + 0 < NN) v.x = cnt[idx + 0];
        if (idx + 1 < NN) v.y = cnt[idx + 1];
        if (idx + 2 < NN) v.z = cnt[idx + 2];
        if (idx + 3 < NN) v.w = cnt[idx + 3];
    }
    int s = v.x + v.y + v.z + v.w;
    int lane = t & 63, w = t >> 6;
    int inc = s;
    for (int d = 1; d < 64; d <<= 1) { int u = __shfl_up(inc, d, 64); if (lane >= d) inc += u; }
    __shared__ int wsum[4];
    if (lane == 63) wsum[w] = inc;
    __syncthreads();
    int off = s_off;
    for (int i = 0; i < w; ++i) off += wsum[i];
    int excl = off + inc - s;
    if (idx + 0 < NN) row_ptr[idx + 0] = excl;
    if (idx + 1 < NN) row_ptr[idx + 1] = excl + v.x;
    if (idx + 2 < NN) row_ptr[idx + 2] = excl + v.x + v.y;
    if (idx + 3 < NN) row_ptr[idx + 3] = excl + v.x + v.y + v.z;
    if (b == 0 && t == 0) row_ptr[NN] = s_tot;
}

__global__ void __launch_bounds__(256) k_fill(const int* __restrict__ ei, const int* __restrict__ row_ptr,
                                              int* __restrict__ fill, int* __restrict__ col) {
    int e = blockIdx.x * 256 + threadIdx.x;
    if (e >= NE) return;
    int s = ei[e], d = ei[NE + e];
    if (s != d) {
        int pos = atomicAdd(&fill[d], 1);
        col[row_ptr[d] + pos] = s;
    }
}

// ---------------- prep: pack W_tm to f16 pairs ([cp][k], coalesced) + zero cnt/fil ----------------
// R16 lesson: coalescing is a cross-lane property — lane k reading Wg[c*32+k]
// is consecutive across lanes (coalesced); per-lane-contiguous k-major was 2x slower.

__global__ void __launch_bounds__(256) k_prep(const float* __restrict__ Wtm, uint_t* __restrict__ Wg,
                                              int* __restrict__ cnt) {
    int i = blockIdx.x * 256 + threadIdx.x;
    if (i < 32 * 128) {                           // 4096 entries
        int cp = i >> 5, kk = i & 31;
        Wg[i] = pkh(Wtm[(2 * cp) * CHN + kk], Wtm[(2 * cp + 1) * CHN + kk]);
    }
    for (int z = i; z < 2 * NN; z += gridDim.x * 256) cnt[z] = 0;   // cnt + fil
}

// ---------------- input MLP: h2 = f16(LN(relu(x @ W_in + b_in))); also zeros tm ----------------

#define MLP_NB 8
#define MLP_GROUPS (NN / MLP_NB)   // 6250, exact

__global__ void __launch_bounds__(256) k_mlp(const float* __restrict__ x, const float* __restrict__ W,
                                             const float* __restrict__ b, const float* __restrict__ g,
                                             const float* __restrict__ be, ushort_t* __restrict__ h2,
                                             ushort_t* __restrict__ tm) {
    // zero last_tm_signal (f16, u32-zero covers 2 entries; runs long before flayer)
    uint_t* tz = (uint_t*)tm;
    for (int z = blockIdx.x * 256 + threadIdx.x; z < NN * CHN / 2; z += gridDim.x * 256) tz[z] = 0u;
    __shared__ float xs[4][MLP_NB][HC];     // 16 KB
    int tid = threadIdx.x;
    int wave = tid >> 6, lane = tid & 63;
    float bx = b[2 * lane],  by = b[2 * lane + 1];
    float gx = g[2 * lane],  gy = g[2 * lane + 1];
    float bex = be[2 * lane], bey = be[2 * lane + 1];
    for (int grp = blockIdx.x * 4 + wave; grp < MLP_GROUPS; grp += gridDim.x * 4) {
        int base = grp * MLP_NB;
        #pragma unroll
        for (int nb = 0; nb < MLP_NB; ++nb) {
            float2 xv = *(const float2*)&x[(size_t)(base + nb) * HC + 2 * lane];
            *(float2*)&xs[wave][nb][2 * lane] = xv;
        }
        float ax[MLP_NB], ay[MLP_NB];
        #pragma unroll
        for (int nb = 0; nb < MLP_NB; ++nb) { ax[nb] = bx; ay[nb] = by; }
        // wave-local LDS: compiler inserts lgkmcnt waits; no block barrier needed
        for (int c = 0; c < HC; c += 4) {
            float2 wv0 = *(const float2*)&W[(c + 0) * HC + 2 * lane];
            float2 wv1 = *(const float2*)&W[(c + 1) * HC + 2 * lane];
            float2 wv2 = *(const float2*)&W[(c + 2) * HC + 2 * lane];
            float2 wv3 = *(const float2*)&W[(c + 3) * HC + 2 * lane];
            #pragma unroll
            for (int nb = 0; nb < MLP_NB; ++nb) {
                float4 xv = *(const float4*)&xs[wave][nb][c];
                ax[nb] = fmaf(xv.x, wv0.x, ax[nb]); ay[nb] = fmaf(xv.x, wv0.y, ay[nb]);
                ax[nb] = fmaf(xv.y, wv1.x, ax[nb]); ay[nb] = fmaf(xv.y, wv1.y, ay[nb]);
                ax[nb] = fmaf(xv.z, wv2.x, ax[nb]); ay[nb] = fmaf(xv.z, wv2.y, ay[nb]);
                ax[nb] = fmaf(xv.w, wv3.x, ax[nb]); ay[nb] = fmaf(xv.w, wv3.y, ay[nb]);
            }
        }
        #pragma unroll
        for (int nb = 0; nb < MLP_NB; ++nb) {
            float a0 = fmaxf(ax[nb], 0.f), a1 = fmaxf(ay[nb], 0.f);
            float sm = a0 + a1;
            for (int m = 1; m < 64; m <<= 1) sm += __shfl_xor(sm, m, 64);
            float mu = sm * (1.f / 128.f);
            float d0 = a0 - mu, d1 = a1 - mu;
            float vv = d0 * d0 + d1 * d1;
            for (int m = 1; m < 64; m <<= 1) vv += __shfl_xor(vv, m, 64);
            float inv = rsqrtf(vv * (1.f / 128.f) + LN_EPS);
            float ox = d0 * inv * gx + bex;
            float oy = d1 * inv * gy + bey;
            *(uint_t*)&h2[(size_t)(base + nb) * HC + 2 * lane] = pkh(ox, oy);
        }
    }
}

// ---------------- fused layer: gather + mean + gating + mix + LN (f16 state) ----------------
// R15/R17 proven shape: 1 node/wave, 12500 blocks, LDS 2 KB, VGPR 36, ~61% occ,
// flayer ~53 us. (R16 k-major W and R18 parity-gather both regressed; reverted.)

__global__ void __launch_bounds__(256) k_flayer(
        const ushort_t* __restrict__ h2in, ushort_t* __restrict__ h2out,
        const int* __restrict__ row_ptr, const int* __restrict__ col,
        const uint_t* __restrict__ Wg, const float* __restrict__ btm,
        const float* __restrict__ gall, const float* __restrict__ ball,
        ushort_t* __restrict__ tm, int layer) {
    __shared__ uint_t hm_pk[4][2][64];   // 2 KB: [wave][h|m][pair]
    int tid = threadIdx.x;
    int wave = tid >> 6, lane = tid & 63;
    int k = lane & 31, half = lane >> 5;
    int node = blockIdx.x * 4 + wave;
    int r0 = row_ptr[node], r1 = row_ptr[node + 1];
    int deg = r1 - r0;
    float tmo = h2f(tm[(size_t)node * CHN + k]);   // prefetch, hides under gather
    float bk  = btm[k];
    float gx  = gall[layer * HC + 2 * lane], gy  = gall[layer * HC + 2 * lane + 1];
    float bex = ball[layer * HC + 2 * lane], bey = ball[layer * HC + 2 * lane + 1];
    // ---- gather-sum over in-neighbors: packed-f16 accumulate, 8 loads in flight ----
    half2_t acc = (half2_t)(_Float16)0;
    for (int base = 0; base < deg; base += 64) {
        int nIdx = min(64, deg - base);
        int myc = (base + lane < deg) ? col[r0 + base + lane] : 0;
        int j = 0;
        for (; j + 8 <= nIdx; j += 8) {
            int s0 = __shfl(myc, j,     64);
            int s1 = __shfl(myc, j + 1, 64);
            int s2 = __shfl(myc, j + 2, 64);
            int s3 = __shfl(myc, j + 3, 64);
            int s4 = __shfl(myc, j + 4, 64);
            int s5 = __shfl(myc, j + 5, 64);
            int s6 = __shfl(myc, j + 6, 64);
            int s7 = __shfl(myc, j + 7, 64);
            uint_t v0 = *(const uint_t*)&h2in[(size_t)s0 * HC + 2 * lane];
            uint_t v1 = *(const uint_t*)&h2in[(size_t)s1 * HC + 2 * lane];
            uint_t v2 = *(const uint_t*)&h2in[(size_t)s2 * HC + 2 * lane];
            uint_t v3 = *(const uint_t*)&h2in[(size_t)s3 * HC + 2 * lane];
            uint_t v4 = *(const uint_t*)&h2in[(size_t)s4 * HC + 2 * lane];
            uint_t v5 = *(const uint_t*)&h2in[(size_t)s5 * HC + 2 * lane];
            uint_t v6 = *(const uint_t*)&h2in[(size_t)s6 * HC + 2 * lane];
            uint_t v7 = *(const uint_t*)&h2in[(size_t)s7 * HC + 2 * lane];
            acc += __builtin_bit_cast(half2_t, v0);
            acc += __builtin_bit_cast(half2_t, v1);
            acc += __builtin_bit_cast(half2_t, v2);
            acc += __builtin_bit_cast(half2_t, v3);
            acc += __builtin_bit_cast(half2_t, v4);
            acc += __builtin_bit_cast(half2_t, v5);
            acc += __builtin_bit_cast(half2_t, v6);
            acc += __builtin_bit_cast(half2_t, v7);
        }
        for (; j + 4 <= nIdx; j += 4) {
            int s0 = __shfl(myc, j,     64);
            int s1 = __shfl(myc, j + 1, 64);
            int s2 = __shfl(myc, j + 2, 64);
            int s3 = __shfl(myc, j + 3, 64);
            uint_t v0 = *(const uint_t*)&h2in[(size_t)s0 * HC + 2 * lane];
            uint_t v1 = *(const uint_t*)&h2in[(size_t)s1 * HC + 2 * lane];
            uint_t v2 = *(const uint_t*)&h2in[(size_t)s2 * HC + 2 * lane];
            uint_t v3 = *(const uint_t*)&h2in[(size_t)s3 * HC + 2 * lane];
            acc += __builtin_bit_cast(half2_t, v0);
            acc += __builtin_bit_cast(half2_t, v1);
            acc += __builtin_bit_cast(half2_t, v2);
            acc += __builtin_bit_cast(half2_t, v3);
        }
        for (; j < nIdx; ++j) {
            int s = __shfl(myc, j, 64);
            uint_t v = *(const uint_t*)&h2in[(size_t)s * HC + 2 * lane];
            acc += __builtin_bit_cast(half2_t, v);
        }
    }
    float ax = (float)acc.x, ay = (float)acc.y;
    // ---- self row, mean ----
    uint_t hvp = *(const uint_t*)&h2in[(size_t)node * HC + 2 * lane];
    float h0 = h2f((ushort_t)(hvp & 0xFFFFu)), h1 = h2f((ushort_t)(hvp >> 16));
    float invdeg = 1.f / (float)(deg + 1);
    float m0 = (ax + h0) * invdeg, m1 = (ay + h1) * invdeg;
    hm_pk[wave][0][lane] = hvp;              // raw self row, no repack
    hm_pk[wave][1][lane] = pkh(m0, m1);
    // wave-local LDS: compiler inserts the lgkmcnt wait; no block barrier needed
    // ---- z_k: half 0 = h . W[0:128,k], half 1 = m . W[128:256,k] (v_dot2) ----
    const uint_t* sp = &hm_pk[wave][half][0];
    const uint_t* wp = Wg + (size_t)(half * 64) * CHN + k;
    float z = 0.f;
    #pragma unroll
    for (int i = 0; i < 16; ++i) {
        uint4 s4 = *(const uint4*)&sp[4 * i];       // LDS broadcast
        uint_t w0 = wp[(4 * i + 0) * CHN];          // cross-lane coalesced, L1-hot
        uint_t w1 = wp[(4 * i + 1) * CHN];
        uint_t w2 = wp[(4 * i + 2) * CHN];
        uint_t w3 = wp[(4 * i + 3) * CHN];
        z = dot2h(s4.x, w0, z);
        z = dot2h(s4.y, w1, z);
        z = dot2h(s4.z, w2, z);
        z = dot2h(s4.w, w3, z);
    }
    z += __shfl_xor(z, 32, 64);      // combine halves -> full z_k on all lanes
    z += bk;
    // ---- softmax over 32 gates (width-32: halves identical) ----
    float mx = z;
    for (int m = 1; m < 32; m <<= 1) mx = fmaxf(mx, __shfl_xor(mx, m, 32));
    float e = __expf(z - mx);
    float se = e;
    for (int m = 1; m < 32; m <<= 1) se += __shfl_xor(se, m, 32);
    float p = e / se;
    // inclusive cumsum over gate index
    float cum = p;
    for (int d = 1; d < 32; d <<= 1) {
        float t2 = __shfl_up(cum, d, 32);
        if (k >= d) cum += t2;
    }
    float raw = tmo + (1.f - tmo) * cum;
    if (half == 0) tm[(size_t)node * CHN + k] = f2h(raw);
    // sig for channels (2*lane, 2*lane+1): gate = lane>>1
    float sig = __shfl(raw, lane >> 1, 64);
    float v0 = h0 * sig + m0 * (1.f - sig);
    float v1 = h1 * sig + m1 * (1.f - sig);
    // ---- LN over 128 ch (width-64 reduce, 2 ch/lane) ----
    float sm = v0 + v1;
    for (int m = 1; m < 64; m <<= 1) sm += __shfl_xor(sm, m, 64);
    float mu = sm * (1.f / 128.f);
    float d0 = v0 - mu, d1 = v1 - mu;
    float vv = d0 * d0 + d1 * d1;
    for (int m = 1; m < 64; m <<= 1) vv += __shfl_xor(vv, m, 64);
    float inv = rsqrtf(vv * (1.f / 128.f) + LN_EPS);
    *(uint_t*)&h2out[(size_t)node * HC + 2 * lane] = pkh(d0 * inv * gx + bex,
                                                         d1 * inv * gy + bey);
}

// ---------------- global mean pool (batch is sorted), f16 input ----------------

__global__ void __launch_bounds__(1024) k_pool(const ushort_t* __restrict__ h2, const int* __restrict__ batch,
                                               float* __restrict__ out) {
    __shared__ float red[8][HC];
    int g = blockIdx.x;
    int tid = threadIdx.x;
    int c = tid & (HC - 1);
    int w = tid >> 7;          // 0..7 node-slice
    int a = 0, bnd = NN;
    while (a < bnd) { int mid = (a + bnd) >> 1; if (batch[mid] < g) a = mid + 1; else bnd = mid; }
    int start = a;
    bnd = NN;
    while (a < bnd) { int mid = (a + bnd) >> 1; if (batch[mid] <= g) a = mid + 1; else bnd = mid; }
    int end = a;
    float acc = 0.f;
    for (int n = start + w; n < end; n += 8) acc += h2f(h2[(size_t)n * HC + c]);
    red[w][c] = acc;
    __syncthreads();
    if (w == 0) {
        float s = red[0][c] + red[1][c] + red[2][c] + red[3][c]
                + red[4][c] + red[5][c] + red[6][c] + red[7][c];
        int count = end - start;
        out[g * HC + c] = s / (float)max(count, 1);
    }
}

// ---------------- launch ----------------

extern "C" void kernel_launch(void* const* d_in, const int* in_sizes, int n_in,
                              void* d_out, int out_size, void* d_ws, size_t ws_size,
                              hipStream_t stream) {
    const float* x     = (const float*)d_in[0];
    const int*   ei    = (const int*)d_in[1];
    const int*   batch = (const int*)d_in[2];
    const float* W_in  = (const float*)d_in[3];
    const float* b_in  = (const float*)d_in[4];
    const float* g_in  = (const float*)d_in[5];
    const float* be_in = (const float*)d_in[6];
    const float* W_tm  = (const float*)d_in[7];
    const float* b_tm  = (const float*)d_in[8];
    const float* tm_g  = (const float*)d_in[9];
    const float* tm_b  = (const float*)d_in[10];
    float* out = (float*)d_out;

    char* ws = (char*)d_ws;
    int*      cnt = (int*)(ws + 0);              // NN ints
    int*      fil = (int*)(ws + 200000);         // NN ints (contiguous after cnt)
    int*      rp  = (int*)(ws + 400000);         // NN+1 ints
    int*      col = (int*)(ws + 600004);         // NE ints   (ends at 3,000,004)
    ushort_t* h2A = (ushort_t*)(ws + 3000064);   // NN*HC f16 (12.8 MB)
    ushort_t* h2B = (ushort_t*)(ws + 15800064);  // NN*HC f16 (12.8 MB)
    ushort_t* tm  = (ushort_t*)(ws + 28600064);  // NN*CHN f16 (3.2 MB)
    int*      bsum = (int*)(ws + 35000064);      // SC_BLOCKS ints
    uint_t*   Wg   = (uint_t*)(ws + 35000576);   // 4096 u32 packed f16 W (16 KB, [cp][k])

    k_prep<<<64, 256, 0, stream>>>(W_tm, Wg, cnt);      // pack W + zero cnt/fil
    k_hist<<<(NE + 255) / 256, 256, 0, stream>>>(ei, cnt);
    k_scanA<<<SC_BLOCKS, 256, 0, stream>>>(cnt, bsum);
    k_scanC<<<SC_BLOCKS, 256, 0, stream>>>(cnt, bsum, rp);   // scanB folded in
    k_fill<<<(NE + 255) / 256, 256, 0, stream>>>(ei, rp, fil, col);

    k_mlp<<<1563, 256, 0, stream>>>(x, W_in, b_in, g_in, be_in, h2A, tm);  // also zeros tm

    k_flayer<<<NN / 4, 256, 0, stream>>>(h2A, h2B, rp, col, Wg, b_tm, tm_g, tm_b, tm, 0);
    k_flayer<<<NN / 4, 256, 0, stream>>>(h2B, h2A, rp, col, Wg, b_tm, tm_g, tm_b, tm, 1);
    k_flayer<<<NN / 4, 256, 0, stream>>>(h2A, h2B, rp, col, Wg, b_tm, tm_g, tm_b, tm, 2);

    k_pool<<<NG, 1024, 0, stream>>>(h2B, batch, out);
}